// Round 6
// baseline (291.523 us; speedup 1.0000x reference)
//
#include <hip/hip_runtime.h>

#define NN 50000
#define EE 800000
#define RR 8
#define DD 128
#define SS (NN*RR)        // 400000 segments
#define TE (2*EE)         // 1600000 directed edges
#define NB 782            // dst buckets of 64 nodes
#define NBK 782           // partition blocks, 2048 directed edges each
#define CH 2048           // edges per partition block
#define NS (NB*NBK)       // 611524 scan elements
#define NSB 598           // ceil(NS/1024) scan1 blocks
#define MAXB 2816         // per-bucket edge bound (mean 2046, sigma~45)

typedef __attribute__((ext_vector_type(8))) short bf16x8;
typedef __attribute__((ext_vector_type(4))) float f32x4;

__device__ __forceinline__ unsigned short f2bf(float f){
  unsigned int u = __float_as_uint(f);
  u += 0x7fffu + ((u >> 16) & 1u);   // round-to-nearest-even
  return (unsigned short)(u >> 16);
}
__device__ __forceinline__ float bf_lo(unsigned int w){ return __uint_as_float(w << 16); }
__device__ __forceinline__ float bf_hi(unsigned int w){ return __uint_as_float(w & 0xffff0000u); }

__device__ __forceinline__ void acc8(float* a, uint4 u){
  a[0] += bf_lo(u.x); a[1] += bf_hi(u.x);
  a[2] += bf_lo(u.y); a[3] += bf_hi(u.y);
  a[4] += bf_lo(u.z); a[5] += bf_hi(u.z);
  a[6] += bf_lo(u.w); a[7] += bf_hi(u.w);
}
__device__ __forceinline__ unsigned int pack2(float a, float b){
  return ((unsigned int)f2bf(b) << 16) | (unsigned int)f2bf(a);
}

// directed edge j in [0,TE): j<EE forward (s->d), else reversed
__device__ __forceinline__ void dir_edge(const int* ei, const int* et, int j,
                                         int& s, int& d, int& t){
  if (j < EE){ s = ei[j]; d = ei[EE + j]; t = et[j]; }
  else { int jj = j - EE; s = ei[EE + jj]; d = ei[jj]; t = et[jj]; }
}

// ---- A1: per-(bucket,block) histogram + fused x/W bf16 conversion ---------
__global__ __launch_bounds__(256) void k_hist(const int* __restrict__ ei,
                                              const int* __restrict__ et,
                                              int* __restrict__ hist,
                                              const float* __restrict__ x,
                                              const float* __restrict__ w,
                                              const float* __restrict__ sw,
                                              unsigned short* __restrict__ xb,
                                              unsigned short* __restrict__ wb){
  __shared__ int h[NB];
  int tid = threadIdx.x, bid = blockIdx.x;
  for (int i = tid; i < NB; i += 256) h[i] = 0;
  __syncthreads();
  int j0 = bid*CH;
  for (int k = tid; k < CH; k += 256){
    int j = j0 + k;
    if (j < TE){
      int s, d, t; dir_edge(ei, et, j, s, d, t);
      atomicAdd(&h[d >> 6], 1);           // LDS atomic
    }
  }
  __syncthreads();
  for (int i = tid; i < NB; i += 256) hist[i*NBK + bid] = h[i];

  // fused conversions (independent work; fills latency bubbles)
  const int M1 = NN*DD/4;                 // 1,600,000 float4 groups
  const int GT = NBK*256;                 // grid stride
  for (int i = bid*256 + tid; i < M1 + 9*DD*DD; i += GT){
    if (i < M1){
      float4 v = ((const float4*)x)[i];
      ushort4 o;
      o.x = f2bf(v.x); o.y = f2bf(v.y); o.z = f2bf(v.z); o.w = f2bf(v.w);
      ((ushort4*)xb)[i] = o;
    } else {
      int j = i - M1;
      int r = j >> 14; int rem = j & 16383; int n = rem >> 7; int kk = rem & 127;
      float v = (r < 8) ? w[r*16384 + kk*128 + n] : sw[kk*128 + n];
      wb[j] = f2bf(v);
    }
  }
}

// ---- scan over NS elements (in-place exclusive), 3 kernels ----------------
__global__ __launch_bounds__(256) void k_scan1(int* __restrict__ hist,
                                               int* __restrict__ blksum){
  __shared__ int sd[256];
  int b = blockIdx.x, tid = threadIdx.x;
  int base = b*1024 + tid*4;
  int v0 = (base+0 < NS) ? hist[base+0] : 0;
  int v1 = (base+1 < NS) ? hist[base+1] : 0;
  int v2 = (base+2 < NS) ? hist[base+2] : 0;
  int v3 = (base+3 < NS) ? hist[base+3] : 0;
  int ts = v0+v1+v2+v3;
  sd[tid] = ts; __syncthreads();
  for (int o = 1; o < 256; o <<= 1){
    int t = (tid >= o) ? sd[tid-o] : 0;
    __syncthreads();
    sd[tid] += t;
    __syncthreads();
  }
  int ex = sd[tid] - ts;
  if (base+0 < NS) hist[base+0] = ex; ex += v0;
  if (base+1 < NS) hist[base+1] = ex; ex += v1;
  if (base+2 < NS) hist[base+2] = ex; ex += v2;
  if (base+3 < NS) hist[base+3] = ex;
  if (tid == 255) blksum[b] = sd[255];
}

__global__ __launch_bounds__(640) void k_scan2(int* __restrict__ blksum, int nb){
  __shared__ int sd[640];
  int tid = threadIdx.x;
  int v = (tid < nb) ? blksum[tid] : 0;
  sd[tid] = v; __syncthreads();
  for (int o = 1; o < 640; o <<= 1){
    int t = (tid >= o) ? sd[tid-o] : 0;
    __syncthreads();
    sd[tid] += t;
    __syncthreads();
  }
  if (tid < nb) blksum[tid] = sd[tid] - v;   // exclusive
}

__global__ __launch_bounds__(256) void k_scan3(int* __restrict__ hist,
                                               const int* __restrict__ blksum){
  int i = blockIdx.x*blockDim.x + threadIdx.x;
  if (i < NS) hist[i] += blksum[i >> 10];
}

// ---- A3: place packed edges into bucket slices ----------------------------
// packed: src (17b) | dstlo (6b @17) | rel (3b @23)
__global__ __launch_bounds__(256) void k_part(const int* __restrict__ ei,
                                              const int* __restrict__ et,
                                              const int* __restrict__ S,
                                              unsigned int* __restrict__ P){
  __shared__ int cur[NB];
  int tid = threadIdx.x, bid = blockIdx.x;
  for (int i = tid; i < NB; i += 256) cur[i] = S[i*NBK + bid];
  __syncthreads();
  int j0 = bid*CH;
  for (int k = tid; k < CH; k += 256){
    int j = j0 + k;
    if (j < TE){
      int s, d, t; dir_edge(ei, et, j, s, d, t);
      int b = d >> 6;
      int p = atomicAdd(&cur[b], 1);       // LDS atomic rank
      P[p] = (unsigned int)s | ((unsigned int)(d & 63) << 17)
           | ((unsigned int)t << 23);
    }
  }
}

// ---- B: per-bucket counting sort -> offs + esrc ---------------------------
// Stages its slice of P in LDS so esrc may ALIAS P (writes stay in-slice).
__global__ __launch_bounds__(256) void k_build(const unsigned int* __restrict__ P,
                                               const int* __restrict__ S,
                                               int* __restrict__ esrc,
                                               int* __restrict__ offs){
  __shared__ unsigned int Pl[MAXB];
  __shared__ int h[512], cu[512], sd[256];
  int tid = threadIdx.x, b = blockIdx.x;
  int pstart = S[b*NBK];
  int pend   = (b+1 < NB) ? S[(b+1)*NBK] : TE;
  int ne = pend - pstart;
  h[2*tid] = 0; h[2*tid+1] = 0;
  for (int k = tid; k < ne && k < MAXB; k += 256) Pl[k] = P[pstart + k];
  __syncthreads();
  for (int k = tid; k < ne; k += 256){
    unsigned int u = (k < MAXB) ? Pl[k] : P[pstart + k];
    int lseg = (int)(((u >> 17) & 63u)*8u + (u >> 23));
    atomicAdd(&h[lseg], 1);                // LDS atomic
  }
  __syncthreads();
  int v0 = h[2*tid], v1 = h[2*tid+1];
  int ts = v0 + v1;
  sd[tid] = ts; __syncthreads();
  for (int o = 1; o < 256; o <<= 1){
    int t = (tid >= o) ? sd[tid-o] : 0;
    __syncthreads();
    sd[tid] += t;
    __syncthreads();
  }
  int ex = sd[tid] - ts;
  cu[2*tid]   = pstart + ex;
  cu[2*tid+1] = pstart + ex + v0;
  int seg0 = b*512;
  if (seg0 + 2*tid     < SS) offs[seg0 + 2*tid]     = cu[2*tid];
  if (seg0 + 2*tid + 1 < SS) offs[seg0 + 2*tid + 1] = cu[2*tid+1];
  if (b == NB-1 && tid == 0) offs[SS] = TE;
  __syncthreads();
  for (int k = tid; k < ne; k += 256){
    unsigned int u = (k < MAXB) ? Pl[k] : P[pstart + k];
    int lseg = (int)(((u >> 17) & 63u)*8u + (u >> 23));
    int r = atomicAdd(&cu[lseg], 1);       // LDS atomic
    esrc[r] = (int)(u & 0x1ffffu);
  }
}

// ---- fused gather + degree-scale + GEMM -----------------------------------
// 16-row tiles -> 3125 blocks (~8 resident blocks/CU = 32 waves/CU cap).
// Each 16-lane group owns one dst row; wave computes out cols [w*32, w*32+32).
__global__ __launch_bounds__(256) void k_fused(
    const unsigned short* __restrict__ xb,
    const unsigned short* __restrict__ wb,
    const int* __restrict__ offs,
    const int* __restrict__ esrc,
    float* __restrict__ out)
{
  __shared__ __align__(16) unsigned short Alds[2][16][136]; // +8 pad: 2-way alias (free)
  const int tid  = threadIdx.x;
  const int wave = tid >> 6, lane = tid & 63;
  const int l15  = lane & 15, quad = lane >> 4;
  const int g    = quad;
  const int gl   = l15;
  const int gbase = g << 4;
  const int rowbase = blockIdx.x * 16;

  f32x4 C0 = (f32x4)(0.f), C1 = (f32x4)(0.f);

  auto gather = [&](int rr, int b){
    int v = 0;
    if (rr < 8 && lane < 8){
      int gdj = rowbase + wave*4 + (lane >> 1);
      if (gdj < NN) v = offs[gdj*8 + rr + (lane & 1)];
    }
    int rowl = wave*4 + g;            // group's row within 16-row tile
    int gd   = rowbase + rowl;
    uint4 u = make_uint4(0u,0u,0u,0u);
    if (rr == 8){
      if (gd < NN) u = *(const uint4*)(xb + (size_t)gd*DD + gl*8);
    } else {
      int off = __shfl(v, 2*g);
      int end = __shfl(v, 2*g + 1);
      int cnt = (gd < NN) ? (end - off) : 0;
      float a[8] = {0.f,0.f,0.f,0.f,0.f,0.f,0.f,0.f};
      int idxv = 0;
      if (gl < cnt) idxv = esrc[off + gl];
      int cm = cnt < 16 ? cnt : 16;
      int e = 0;
      for (; e + 4 <= cm; e += 4){
        int s0 = __shfl(idxv, gbase + e + 0);
        int s1 = __shfl(idxv, gbase + e + 1);
        int s2 = __shfl(idxv, gbase + e + 2);
        int s3 = __shfl(idxv, gbase + e + 3);
        uint4 u0 = *(const uint4*)(xb + (size_t)s0*DD + gl*8);
        uint4 u1 = *(const uint4*)(xb + (size_t)s1*DD + gl*8);
        uint4 u2 = *(const uint4*)(xb + (size_t)s2*DD + gl*8);
        uint4 u3 = *(const uint4*)(xb + (size_t)s3*DD + gl*8);
        acc8(a, u0); acc8(a, u1); acc8(a, u2); acc8(a, u3);
      }
      for (; e < cm; ++e){
        int s0 = __shfl(idxv, gbase + e);
        uint4 u0 = *(const uint4*)(xb + (size_t)s0*DD + gl*8);
        acc8(a, u0);
      }
      for (int e2 = 16; e2 < cnt; ++e2){
        int s0 = esrc[off + e2];
        uint4 u0 = *(const uint4*)(xb + (size_t)s0*DD + gl*8);
        acc8(a, u0);
      }
      float sc = (cnt > 0) ? (1.0f / (float)cnt) : 0.f;
      u.x = pack2(a[0]*sc, a[1]*sc);
      u.y = pack2(a[2]*sc, a[3]*sc);
      u.z = pack2(a[4]*sc, a[5]*sc);
      u.w = pack2(a[6]*sc, a[7]*sc);
    }
    *(uint4*)&Alds[b][rowl][gl*8] = u;
  };

  gather(0, 0);
  __syncthreads();

  #pragma unroll 1
  for (int rr = 0; rr < 9; ++rr){
    int b = rr & 1;
    if (rr < 8) gather(rr + 1, b ^ 1);   // overlaps MFMA below

    const unsigned short* wr = wb + rr * 16384;
    bf16x8 bfrag[2][4];
    #pragma unroll
    for (int nt = 0; nt < 2; ++nt)
      #pragma unroll
      for (int ks = 0; ks < 4; ++ks)
        bfrag[nt][ks] = *(const bf16x8*)(wr + (wave*32 + nt*16 + l15)*128 + ks*32 + quad*8);

    #pragma unroll
    for (int ks = 0; ks < 4; ++ks){
      bf16x8 af = *(const bf16x8*)&Alds[b][l15][ks*32 + quad*8];
      C0 = __builtin_amdgcn_mfma_f32_16x16x32_bf16(af, bfrag[0][ks], C0, 0, 0, 0);
      C1 = __builtin_amdgcn_mfma_f32_16x16x32_bf16(af, bfrag[1][ks], C1, 0, 0, 0);
    }
    __syncthreads();
  }

  // epilogue: C/D layout col = lane&15, row = quad*4 + reg
  #pragma unroll
  for (int i = 0; i < 4; ++i){
    int row = quad*4 + i;
    int gd  = rowbase + row;
    if (gd < NN){
      out[gd*DD + wave*32 +      l15] = C0[i];
      out[gd*DD + wave*32 + 16 + l15] = C1[i];
    }
  }
}

// ---- workspace layout (bytes) ---------------------------------------------
// xb      @ 0          : NN*DD*2   = 12,800,000
// esrc/P  @ 12,800,000 : TE*4      = 6,400,000   (aliased: k_build stages in LDS)
// offs    @ 19,200,000 : (SS+1)*4 -> 1,600,016
// wb      @ 20,800,016 : 9*DD*DD*2 = 294,912
// hist    @ 21,094,928 : NS*4      = 2,446,096
// blksum  @ 23,541,024 : 598*4     = 2,392
// total 23,543,416
extern "C" void kernel_launch(void* const* d_in, const int* in_sizes, int n_in,
                              void* d_out, int out_size, void* d_ws, size_t ws_size,
                              hipStream_t stream){
  const float* x  = (const float*)d_in[0];
  const float* w  = (const float*)d_in[1];
  const float* sw = (const float*)d_in[2];
  const int*   ei = (const int*)d_in[3];
  const int*   et = (const int*)d_in[4];
  float* out = (float*)d_out;
  char* ws = (char*)d_ws;

  if (ws_size < (size_t)23550000) return;

  unsigned short* xb = (unsigned short*)(ws + 0);
  unsigned int*    P = (unsigned int*)(ws + 12800000);
  int*          esrc = (int*)(ws + 12800000);        // alias with P (safe: staged)
  int*          offs = (int*)(ws + 19200000);
  unsigned short* wb = (unsigned short*)(ws + 20800016);
  int*          hist = (int*)(ws + 21094928);
  int*        blksum = (int*)(ws + 23541024);

  k_hist <<<NBK, 256, 0, stream>>>(ei, et, hist, x, w, sw, xb, wb);
  k_scan1<<<NSB, 256, 0, stream>>>(hist, blksum);
  k_scan2<<<1, 640, 0, stream>>>(blksum, NSB);
  k_scan3<<<(NS + 255)/256, 256, 0, stream>>>(hist, blksum);
  k_part <<<NBK, 256, 0, stream>>>(ei, et, hist, P);
  k_build<<<NB, 256, 0, stream>>>(P, hist, esrc, offs);
  k_fused<<<(NN + 15)/16, 256, 0, stream>>>(xb, wb, offs, esrc, out);
}